// Round 17
// baseline (7321.897 us; speedup 1.0000x reference)
//
#include <hip/hip_runtime.h>
#include <stdint.h>

#define HW 25600
#define C  2048
#define K  10
#define NITER 20
#define RTOL_ 1e-5f
#define ATOL_ 1e-6f
#define NCH 8           // label c-chunks
#define CCH (C / NCH)   // 256 channels per chunk

// ---------------- device state (fully re-derived every launch) ----------------
__device__ __align__(4) unsigned char g_valid[HW];
__device__ __align__(4) unsigned char g_labels[HW];
__device__ float g_tok_sq[HW];
__device__ float g_r[HW];
__device__ __align__(16) float  g_cent[K * C];
__device__ __align__(16) double g_cent64[K * C];   // f64 mirror for scalar loads
__device__ float g_csq[K];
__device__ int   g_counts[K];
__device__ unsigned g_done;
__device__ unsigned g_ticket;
// scratch for parallel f64 partial reductions (f64 reassociation is safe:
// noise ~1e-16 rel, absorbed by the final f64->f32 rounding — R10-R16 evidence)
__device__ double g_part[NCH * K * HW];    // label partial dots (16.4 MB)
__device__ double g_spart[K * C];          // channel sums (f64)
__device__ double g_psq[8 * HW];           // prep partial sumsq
__device__ __align__(4) unsigned char g_pany[8 * HW];

// ---------------- prep A: per-chunk f64 partial sumsq + any ----------------
__global__ __launch_bounds__(256) void prepA_kernel(const float* __restrict__ X,
                                                    const float* __restrict__ mask) {
    const int chunk = blockIdx.x & 7;
    const int hw = (blockIdx.x >> 3) * 256 + threadIdx.x;
    const float mb = (mask[hw] > 0.0f) ? 1.0f : 0.0f;
    const float* xp = X + hw + (size_t)(chunk * 256) * HW;
    double a = 0.0;
    int n = 0;
    for (int cc = 0; cc < 256; ++cc) {
        float v = xp[(size_t)cc * HW] * mb;   // exact f32 product (mb in {0,1})
        n |= (v != 0.0f);
        a = fma((double)v, (double)v, a);
    }
    g_psq[chunk * HW + hw] = a;
    g_pany[chunk * HW + hw] = (unsigned char)n;
}

// ---------------- threefry2x32 (JAX partitionable), key=(0,42) ----------------
// counter=(hi=0, lo=i); 32-bit draw = out0 ^ out1 (CONFIRMED R6/R10-R16).
__device__ __forceinline__ uint32_t rotl32(uint32_t v, int d) {
    return (v << d) | (v >> (32 - d));
}

// ---------------- prepB + rng fused ----------------
__global__ __launch_bounds__(256) void rng_kernel() {
    const int hw = blockIdx.x * 256 + threadIdx.x;
    double s0 = (g_psq[0 * HW + hw] + g_psq[1 * HW + hw]) +
                (g_psq[2 * HW + hw] + g_psq[3 * HW + hw]);
    double s1 = (g_psq[4 * HW + hw] + g_psq[5 * HW + hw]) +
                (g_psq[6 * HW + hw] + g_psq[7 * HW + hw]);
    g_tok_sq[hw] = (float)(s0 + s1);
    int any = 0;
#pragma unroll
    for (int j = 0; j < 8; ++j) any |= g_pany[j * HW + hw];
    g_valid[hw] = any ? 1 : 0;

    const uint32_t k0 = 0u, k1 = 42u;
    uint32_t ks[3] = {k0, k1, k0 ^ k1 ^ 0x1BD11BDAu};
    uint32_t x0 = 0u + ks[0];
    uint32_t x1 = (uint32_t)hw + ks[1];
    const int rot[2][4] = {{13, 15, 26, 6}, {17, 29, 16, 24}};
#pragma unroll
    for (int g = 0; g < 5; ++g) {
#pragma unroll
        for (int j = 0; j < 4; ++j) {
            x0 += x1;
            x1 = rotl32(x1, rot[g & 1][j]);
            x1 ^= x0;
        }
        x0 += ks[(g + 1) % 3];
        x1 += ks[(g + 2) % 3] + (uint32_t)(g + 1);
    }
    uint32_t bits = x0 ^ x1;
    float u = __uint_as_float((bits >> 9) | 0x3f800000u) - 1.0f;
    g_r[hw] = any ? u : 2.0f;
}

// ---------------- init selection + gather + zero + csq ----------------
__global__ __launch_bounds__(1024) void select_kernel(const float* __restrict__ X,
                                                      const float* __restrict__ mask) {
    __shared__ unsigned long long wmin[16];
    __shared__ unsigned long long bcast;
    __shared__ int sh_idx[K];
    const int tid = threadIdx.x;
    const int lane = tid & 63, wv = tid >> 6;
    unsigned long long key[25];
#pragma unroll
    for (int j = 0; j < 25; ++j) {
        const int i = j * 1024 + tid;
        key[j] = ((unsigned long long)__float_as_uint(g_r[i]) << 32) | (unsigned)i;
    }
    for (int round = 0; round < K; ++round) {
        unsigned long long best = ~0ull;
#pragma unroll
        for (int j = 0; j < 25; ++j) best = (key[j] < best) ? key[j] : best;
#pragma unroll
        for (int off = 32; off > 0; off >>= 1) {
            unsigned long long o = __shfl_down(best, off, 64);
            best = (o < best) ? o : best;
        }
        if (lane == 0) wmin[wv] = best;
        __syncthreads();
        if (wv == 0) {
            unsigned long long b = (lane < 16) ? wmin[lane] : ~0ull;
#pragma unroll
            for (int off = 8; off > 0; off >>= 1) {
                unsigned long long o = __shfl_down(b, off, 64);
                b = (o < b) ? o : b;
            }
            if (lane == 0) { bcast = b; sh_idx[round] = (int)(b & 0xffffffffu); }
        }
        __syncthreads();
        const unsigned long long g = bcast;
#pragma unroll
        for (int j = 0; j < 25; ++j) if (key[j] == g) key[j] = ~0ull;
    }
    for (int e = tid; e < K * C; e += 1024) {
        int k = e >> 11, c = e & (C - 1);
        int id = sh_idx[k];
        float mb = (mask[id] > 0.0f) ? 1.0f : 0.0f;
        float v = X[(size_t)c * HW + id] * mb;
        g_cent[e] = v;
        g_cent64[e] = (double)v;
    }
    if (tid < K) g_counts[tid] = 0;
    if (tid == 0) { g_done = 0u; g_ticket = 0u; }
    __syncthreads();
    if (wv < K) {
        double a = 0.0;
        for (int c = lane; c < C; c += 64) {
            double v = (double)g_cent[wv * C + c];
            a = fma(v, v, a);
        }
#pragma unroll
        for (int off = 32; off > 0; off >>= 1) a += __shfl_down(a, off, 64);
        if (lane == 0) g_csq[wv] = (float)a;
    }
}

// ---------------- label pass 1: f64 partial dots, scalar-cached cent ----------------
__global__ __launch_bounds__(256) void label1_kernel(const float* __restrict__ X) {
    if (g_done) return;
    const int chunk = blockIdx.x & (NCH - 1);
    const int hw = (blockIdx.x >> 3) * 256 + threadIdx.x;
    const int c0 = chunk * CCH;
    const double* __restrict__ cp = g_cent64 + c0;  // [k*C + cc], wave-uniform
    double acc[K];
#pragma unroll
    for (int k = 0; k < K; ++k) acc[k] = 0.0;
    const float* xp = X + hw + (size_t)c0 * HW;
#pragma unroll 4
    for (int cc = 0; cc < CCH; ++cc) {
        const double x = (double)xp[(size_t)cc * HW];
#pragma unroll
        for (int k = 0; k < K; ++k) acc[k] = fma(x, cp[k * C + cc], acc[k]);
    }
#pragma unroll
    for (int k = 0; k < K; ++k) g_part[(chunk * K + k) * HW + hw] = acc[k];
}

// ---------------- label pass 2: combine 8, f32 d2 grid, argmin, hist ----------------
__global__ __launch_bounds__(256) void label2_kernel() {
#pragma clang fp contract(off)
    if (g_done) return;
    __shared__ int shist[K];
    const int t = threadIdx.x;
    if (t < K) shist[t] = 0;
    __syncthreads();
    const int hw = blockIdx.x * 256 + t;
    const float tsq = g_tok_sq[hw];
    float best = INFINITY;
    int bl = 0;
#pragma unroll
    for (int k = 0; k < K; ++k) {
        double p[NCH];
#pragma unroll
        for (int j = 0; j < NCH; ++j) p[j] = g_part[(j * K + k) * HW + hw];
        double d = ((p[0] + p[1]) + (p[2] + p[3])) + ((p[4] + p[5]) + (p[6] + p[7]));
        float dotf = (float)d;               // correctly-rounded f32 dot
        float twod = 2.0f * dotf;            // exact
        float d2 = (tsq - twod) + g_csq[k];  // reference's f32 grid
        if (d2 < best) { best = d2; bl = k; }
    }
    const int valid = g_valid[hw];
    g_labels[hw] = valid ? (unsigned char)bl : (unsigned char)255;
    if (valid) atomicAdd(&shist[bl], 1);
    __syncthreads();
    if (t < K) atomicAdd(&g_counts[t], shist[t]);
}

// ---------------- sum pass + fused update (last-block-done) ----------------
// 2048 blocks; per-channel LDS-slot sums identical to R16. Each block
// publishes g_spart, fences, takes a ticket; the last block runs the full
// update phase (conv check, centroid/csq update, output write) inline.
__global__ __launch_bounds__(256) void sum_kernel(const float* __restrict__ X,
                                                  int last, float* __restrict__ out) {
#pragma clang fp contract(off)
    const unsigned done = g_done;
    const int t = threadIdx.x;
    const int wv = t >> 6, lane = t & 63;
    if (!done) {
        __shared__ double sacc[4][64 * 11];  // 22.5 KB
        const int c = blockIdx.x;
        double* slots = &sacc[wv][lane * 11];
#pragma unroll
        for (int k = 0; k < 11; ++k) slots[k] = 0.0;
        const int base = wv * (HW / 4);  // quarter-row (1600 float4)
        const float4* xr = (const float4*)(X + (size_t)c * HW + base);
        const unsigned* lw = (const unsigned*)(g_labels + base);
        for (int it = 0; it < 25; ++it) {
            const int idx = it * 64 + lane;
            const float4 x = xr[idx];
            const unsigned w = lw[idx];
            const int l0 = min((int)(w & 255u), 10);
            const int l1 = min((int)((w >> 8) & 255u), 10);
            const int l2 = min((int)((w >> 16) & 255u), 10);
            const int l3 = min((int)(w >> 24), 10);
            slots[l0] += (double)x.x;
            slots[l1] += (double)x.y;
            slots[l2] += (double)x.z;
            slots[l3] += (double)x.w;
        }
        double acc[K];
#pragma unroll
        for (int k = 0; k < K; ++k) acc[k] = slots[k];
#pragma unroll
        for (int k = 0; k < K; ++k) {
#pragma unroll
            for (int off = 32; off > 0; off >>= 1)
                acc[k] += __shfl_down(acc[k], off, 64);
        }
        __shared__ double comb[4][K];
        if (lane == 0) {
#pragma unroll
            for (int k = 0; k < K; ++k) comb[wv][k] = acc[k];
        }
        __syncthreads();
        if (t < K)
            g_spart[t * C + c] = (comb[0][t] + comb[1][t]) + (comb[2][t] + comb[3][t]);
    }
    // ---- ticket: last block performs the update phase ----
    __threadfence();
    __shared__ unsigned s_tick;
    if (t == 0) s_tick = atomicAdd(&g_ticket, 1u);
    __syncthreads();
    if (s_tick != (unsigned)(gridDim.x - 1)) return;
    __threadfence();
    if (t == 0) g_ticket = 0u;  // reset for next dispatch (visible at boundary)

    __shared__ float sh_counts[K];
    __shared__ int s_conv;
    if (t == 0) s_conv = 1;
    if (t < K) sh_counts[t] = (float)g_counts[t];
    __syncthreads();
    const bool dn = (done != 0);
    int convLocal = 1;
    for (int j = 0; j < 80; ++j) {
        int e = t + j * 256;
        int k = e >> 11;
        float cnt = sh_counts[k];
        float cv = g_cent[e];
        float sumf = (float)g_spart[e];   // f64 total -> f32 once
        float nv = (cnt > 0.0f) ? (sumf / fmaxf(cnt, 1.0f)) : cv;
        float tol = RTOL_ * fabsf(nv);   // rounded mul
        tol = ATOL_ + tol;               // rounded add
        if (!(fabsf(cv - nv) <= tol)) convLocal = 0;
    }
    if (!convLocal) atomicAnd(&s_conv, 0);
    __syncthreads();
    const bool conv = (s_conv != 0);
    const bool upd = (!dn && !conv);
    for (int j = 0; j < 80; ++j) {
        int e = t + j * 256;
        int k = e >> 11;
        float cnt = sh_counts[k];
        float cv = g_cent[e];
        float sumf = (float)g_spart[e];
        float nv = (cnt > 0.0f) ? (sumf / fmaxf(cnt, 1.0f)) : cv;
        float fv = upd ? nv : cv;
        if (upd) { g_cent[e] = fv; g_cent64[e] = (double)fv; }
        if (last) out[e] = fv;
    }
    if (t == 0 && conv && !dn) g_done = 1u;
    if (t < K) g_counts[t] = 0;
    __syncthreads();
    if (upd) {
        // csq from updated centroids: 4 waves cover clusters k = wv, wv+4, wv+8
        for (int k = wv; k < K; k += 4) {
            double a = 0.0;
            for (int c = lane; c < C; c += 64) {
                double v = (double)g_cent[k * C + c];
                a = fma(v, v, a);
            }
#pragma unroll
            for (int off = 32; off > 0; off >>= 1) a += __shfl_down(a, off, 64);
            if (lane == 0) g_csq[k] = (float)a;
        }
    }
}

extern "C" void kernel_launch(void* const* d_in, const int* in_sizes, int n_in,
                              void* d_out, int out_size, void* d_ws, size_t ws_size,
                              hipStream_t stream) {
    const float* X = (const float*)d_in[0];     // [2048, 160*160] flat
    const float* mask = (const float*)d_in[1];  // [160*160]
    float* out = (float*)d_out;                 // [10, 2048]
    (void)in_sizes; (void)n_in; (void)out_size; (void)d_ws; (void)ws_size;

    prepA_kernel<<<800, 256, 0, stream>>>(X, mask);
    rng_kernel<<<100, 256, 0, stream>>>();
    select_kernel<<<1, 1024, 0, stream>>>(X, mask);
    for (int it = 0; it < NITER; ++it) {
        label1_kernel<<<800, 256, 0, stream>>>(X);
        label2_kernel<<<100, 256, 0, stream>>>();
        sum_kernel<<<C, 256, 0, stream>>>(X, it == NITER - 1 ? 1 : 0, out);
    }
}

// Round 18
// 2365.406 us; speedup vs baseline: 3.0954x; 3.0954x over previous
//
#include <hip/hip_runtime.h>
#include <stdint.h>

#define HW 25600
#define C  2048
#define K  10
#define NITER 20
#define RTOL_ 1e-5f
#define ATOL_ 1e-6f
#define NCH 8           // label c-chunks
#define CCH (C / NCH)   // 256 channels per chunk

// ---------------- device state (fully re-derived every launch) ----------------
__device__ __align__(4) unsigned char g_valid[HW];
__device__ __align__(4) unsigned char g_labels[HW];
__device__ float g_tok_sq[HW];
__device__ float g_r[HW];
__device__ __align__(16) float  g_cent[K * C];
__device__ __align__(16) double g_cent64[K * C];   // f64 mirror for scalar loads
__device__ float g_csq[K];
__device__ int   g_counts[K];
__device__ unsigned g_done;
// scratch for parallel f64 partial reductions (f64 reassociation is safe:
// noise ~1e-16 rel, absorbed by the final f64->f32 rounding — R10-R16 evidence)
__device__ double g_part[NCH * K * HW];    // label partial dots (16.4 MB)
__device__ double g_spart[K * C];          // channel sums (f64)
__device__ double g_psq[8 * HW];           // prep partial sumsq
__device__ __align__(4) unsigned char g_pany[8 * HW];

// ---------------- prep A: per-chunk f64 partial sumsq + any ----------------
__global__ __launch_bounds__(256) void prepA_kernel(const float* __restrict__ X,
                                                    const float* __restrict__ mask) {
    const int chunk = blockIdx.x & 7;
    const int hw = (blockIdx.x >> 3) * 256 + threadIdx.x;
    const float mb = (mask[hw] > 0.0f) ? 1.0f : 0.0f;
    const float* xp = X + hw + (size_t)(chunk * 256) * HW;
    double a = 0.0;
    int n = 0;
    for (int cc = 0; cc < 256; ++cc) {
        float v = xp[(size_t)cc * HW] * mb;   // exact f32 product (mb in {0,1})
        n |= (v != 0.0f);
        a = fma((double)v, (double)v, a);
    }
    g_psq[chunk * HW + hw] = a;
    g_pany[chunk * HW + hw] = (unsigned char)n;
}

// ---------------- threefry2x32 (JAX partitionable), key=(0,42) ----------------
// counter=(hi=0, lo=i); 32-bit draw = out0 ^ out1 (CONFIRMED R6/R10-R16).
__device__ __forceinline__ uint32_t rotl32(uint32_t v, int d) {
    return (v << d) | (v >> (32 - d));
}

// ---------------- prepB + rng fused ----------------
__global__ __launch_bounds__(256) void rng_kernel() {
    const int hw = blockIdx.x * 256 + threadIdx.x;
    double s0 = (g_psq[0 * HW + hw] + g_psq[1 * HW + hw]) +
                (g_psq[2 * HW + hw] + g_psq[3 * HW + hw]);
    double s1 = (g_psq[4 * HW + hw] + g_psq[5 * HW + hw]) +
                (g_psq[6 * HW + hw] + g_psq[7 * HW + hw]);
    g_tok_sq[hw] = (float)(s0 + s1);
    int any = 0;
#pragma unroll
    for (int j = 0; j < 8; ++j) any |= g_pany[j * HW + hw];
    g_valid[hw] = any ? 1 : 0;

    const uint32_t k0 = 0u, k1 = 42u;
    uint32_t ks[3] = {k0, k1, k0 ^ k1 ^ 0x1BD11BDAu};
    uint32_t x0 = 0u + ks[0];
    uint32_t x1 = (uint32_t)hw + ks[1];
    const int rot[2][4] = {{13, 15, 26, 6}, {17, 29, 16, 24}};
#pragma unroll
    for (int g = 0; g < 5; ++g) {
#pragma unroll
        for (int j = 0; j < 4; ++j) {
            x0 += x1;
            x1 = rotl32(x1, rot[g & 1][j]);
            x1 ^= x0;
        }
        x0 += ks[(g + 1) % 3];
        x1 += ks[(g + 2) % 3] + (uint32_t)(g + 1);
    }
    uint32_t bits = x0 ^ x1;
    float u = __uint_as_float((bits >> 9) | 0x3f800000u) - 1.0f;
    g_r[hw] = any ? u : 2.0f;
}

// ---------------- init selection + gather + zero + csq ----------------
__global__ __launch_bounds__(1024) void select_kernel(const float* __restrict__ X,
                                                      const float* __restrict__ mask) {
    __shared__ unsigned long long wmin[16];
    __shared__ unsigned long long bcast;
    __shared__ int sh_idx[K];
    const int tid = threadIdx.x;
    const int lane = tid & 63, wv = tid >> 6;
    unsigned long long key[25];
#pragma unroll
    for (int j = 0; j < 25; ++j) {
        const int i = j * 1024 + tid;
        key[j] = ((unsigned long long)__float_as_uint(g_r[i]) << 32) | (unsigned)i;
    }
    for (int round = 0; round < K; ++round) {
        unsigned long long best = ~0ull;
#pragma unroll
        for (int j = 0; j < 25; ++j) best = (key[j] < best) ? key[j] : best;
#pragma unroll
        for (int off = 32; off > 0; off >>= 1) {
            unsigned long long o = __shfl_down(best, off, 64);
            best = (o < best) ? o : best;
        }
        if (lane == 0) wmin[wv] = best;
        __syncthreads();
        if (wv == 0) {
            unsigned long long b = (lane < 16) ? wmin[lane] : ~0ull;
#pragma unroll
            for (int off = 8; off > 0; off >>= 1) {
                unsigned long long o = __shfl_down(b, off, 64);
                b = (o < b) ? o : b;
            }
            if (lane == 0) { bcast = b; sh_idx[round] = (int)(b & 0xffffffffu); }
        }
        __syncthreads();
        const unsigned long long g = bcast;
#pragma unroll
        for (int j = 0; j < 25; ++j) if (key[j] == g) key[j] = ~0ull;
    }
    for (int e = tid; e < K * C; e += 1024) {
        int k = e >> 11, c = e & (C - 1);
        int id = sh_idx[k];
        float mb = (mask[id] > 0.0f) ? 1.0f : 0.0f;
        float v = X[(size_t)c * HW + id] * mb;
        g_cent[e] = v;
        g_cent64[e] = (double)v;
    }
    if (tid < K) g_counts[tid] = 0;
    if (tid == 0) g_done = 0u;
    __syncthreads();
    if (wv < K) {
        double a = 0.0;
        for (int c = lane; c < C; c += 64) {
            double v = (double)g_cent[wv * C + c];
            a = fma(v, v, a);
        }
#pragma unroll
        for (int off = 32; off > 0; off >>= 1) a += __shfl_down(a, off, 64);
        if (lane == 0) g_csq[wv] = (float)a;
    }
}

// ---------------- label pass 1: f64 partial dots, scalar-cached cent ----------------
__global__ __launch_bounds__(256) void label1_kernel(const float* __restrict__ X) {
    if (g_done) return;
    const int chunk = blockIdx.x & (NCH - 1);
    const int hw = (blockIdx.x >> 3) * 256 + threadIdx.x;
    const int c0 = chunk * CCH;
    const double* __restrict__ cp = g_cent64 + c0;  // [k*C + cc], wave-uniform
    double acc[K];
#pragma unroll
    for (int k = 0; k < K; ++k) acc[k] = 0.0;
    const float* xp = X + hw + (size_t)c0 * HW;
#pragma unroll 4
    for (int cc = 0; cc < CCH; ++cc) {
        const double x = (double)xp[(size_t)cc * HW];
#pragma unroll
        for (int k = 0; k < K; ++k) acc[k] = fma(x, cp[k * C + cc], acc[k]);
    }
#pragma unroll
    for (int k = 0; k < K; ++k) g_part[(chunk * K + k) * HW + hw] = acc[k];
}

// ---------------- label pass 2: combine 8, f32 d2 grid, argmin, hist ----------------
__global__ __launch_bounds__(256) void label2_kernel() {
#pragma clang fp contract(off)
    if (g_done) return;
    __shared__ int shist[K];
    const int t = threadIdx.x;
    if (t < K) shist[t] = 0;
    __syncthreads();
    const int hw = blockIdx.x * 256 + t;
    const float tsq = g_tok_sq[hw];
    float best = INFINITY;
    int bl = 0;
#pragma unroll
    for (int k = 0; k < K; ++k) {
        double p[NCH];
#pragma unroll
        for (int j = 0; j < NCH; ++j) p[j] = g_part[(j * K + k) * HW + hw];
        double d = ((p[0] + p[1]) + (p[2] + p[3])) + ((p[4] + p[5]) + (p[6] + p[7]));
        float dotf = (float)d;               // correctly-rounded f32 dot
        float twod = 2.0f * dotf;            // exact
        float d2 = (tsq - twod) + g_csq[k];  // reference's f32 grid
        if (d2 < best) { best = d2; bl = k; }
    }
    const int valid = g_valid[hw];
    g_labels[hw] = valid ? (unsigned char)bl : (unsigned char)255;
    if (valid) atomicAdd(&shist[bl], 1);
    __syncthreads();
    if (t < K) atomicAdd(&g_counts[t], shist[t]);
}

// ---------------- sum pass: block per channel, slot-major LDS ----------------
// 2048 blocks; slot k of lane l at sacc[wv][k*64 + l]: bank = 2l mod 32
// (k*128 ≡ 0 mod 32) -> 2-way aliasing = free (m136). Per-lane accumulation
// order identical to R16 -> bit-identical f64 sums.
__global__ __launch_bounds__(256) void sum_kernel(const float* __restrict__ X) {
    if (g_done) return;
    __shared__ double sacc[4][11 * 64];  // 22.5 KB
    const int c = blockIdx.x;
    const int wv = threadIdx.x >> 6, lane = threadIdx.x & 63;
    double* slots = &sacc[wv][lane];     // slot k at slots[k*64]
#pragma unroll
    for (int k = 0; k < 11; ++k) slots[k * 64] = 0.0;
    const int base = wv * (HW / 4);      // quarter-row (1600 float4)
    const float4* xr = (const float4*)(X + (size_t)c * HW + base);
    const unsigned* lw = (const unsigned*)(g_labels + base);
    for (int t = 0; t < 25; ++t) {
        const int idx = t * 64 + lane;
        const float4 x = xr[idx];
        const unsigned w = lw[idx];
        const int l0 = min((int)(w & 255u), 10);
        const int l1 = min((int)((w >> 8) & 255u), 10);
        const int l2 = min((int)((w >> 16) & 255u), 10);
        const int l3 = min((int)(w >> 24), 10);
        slots[l0 * 64] += (double)x.x;
        slots[l1 * 64] += (double)x.y;
        slots[l2 * 64] += (double)x.z;
        slots[l3 * 64] += (double)x.w;
    }
    double acc[K];
#pragma unroll
    for (int k = 0; k < K; ++k) acc[k] = slots[k * 64];
#pragma unroll
    for (int k = 0; k < K; ++k) {
#pragma unroll
        for (int off = 32; off > 0; off >>= 1) acc[k] += __shfl_down(acc[k], off, 64);
    }
    __shared__ double comb[4][K];
    if (lane == 0) {
#pragma unroll
        for (int k = 0; k < K; ++k) comb[wv][k] = acc[k];
    }
    __syncthreads();
    if (threadIdx.x < K) {
        const int k = threadIdx.x;
        g_spart[k * C + c] = (comb[0][k] + comb[1][k]) + (comb[2][k] + comb[3][k]);
    }
}

// ---------------- update / convergence / csq ----------------
__global__ __launch_bounds__(1024) void update_kernel(int last, float* __restrict__ out) {
#pragma clang fp contract(off)
    __shared__ float sh_counts[K];
    __shared__ int s_conv;
    __shared__ unsigned s_done;
    const int tid = threadIdx.x;
    if (tid == 0) { s_conv = 1; s_done = g_done; }
    if (tid < K) sh_counts[tid] = (float)g_counts[tid];
    __syncthreads();
    const bool dn = (s_done != 0);
    float newv[20], oldv[20];
    int convLocal = 1;
#pragma unroll
    for (int j = 0; j < 20; ++j) {
        int e = tid + j * 1024;
        int k = e >> 11;
        float cnt = sh_counts[k];
        float cv = g_cent[e];
        float sumf = (float)g_spart[e];   // f64 total -> f32 once
        float nv = (cnt > 0.0f) ? (sumf / fmaxf(cnt, 1.0f)) : cv;
        newv[j] = nv;
        oldv[j] = cv;
        float tol = RTOL_ * fabsf(nv);   // rounded mul
        tol = ATOL_ + tol;               // rounded add
        float diff = fabsf(cv - nv);
        if (!(diff <= tol)) convLocal = 0;
    }
    if (!convLocal) atomicAnd(&s_conv, 0);
    __syncthreads();
    const bool conv = (s_conv != 0);
    const bool upd = (!dn && !conv);
#pragma unroll
    for (int j = 0; j < 20; ++j) {
        int e = tid + j * 1024;
        float fv = upd ? newv[j] : oldv[j];
        if (upd) { g_cent[e] = fv; g_cent64[e] = (double)fv; }
        if (last) out[e] = fv;
    }
    if (tid == 0 && conv && !dn) g_done = 1u;
    if (tid < K) g_counts[tid] = 0;
    __syncthreads();
    const int wv = tid >> 6, lane = tid & 63;
    if (wv < K) {
        double a = 0.0;
        for (int c = lane; c < C; c += 64) {
            double v = (double)g_cent[wv * C + c];
            a = fma(v, v, a);
        }
#pragma unroll
        for (int off = 32; off > 0; off >>= 1) a += __shfl_down(a, off, 64);
        if (lane == 0) g_csq[wv] = (float)a;
    }
}

extern "C" void kernel_launch(void* const* d_in, const int* in_sizes, int n_in,
                              void* d_out, int out_size, void* d_ws, size_t ws_size,
                              hipStream_t stream) {
    const float* X = (const float*)d_in[0];     // [2048, 160*160] flat
    const float* mask = (const float*)d_in[1];  // [160*160]
    float* out = (float*)d_out;                 // [10, 2048]
    (void)in_sizes; (void)n_in; (void)out_size; (void)d_ws; (void)ws_size;

    prepA_kernel<<<800, 256, 0, stream>>>(X, mask);
    rng_kernel<<<100, 256, 0, stream>>>();
    select_kernel<<<1, 1024, 0, stream>>>(X, mask);
    for (int it = 0; it < NITER; ++it) {
        label1_kernel<<<800, 256, 0, stream>>>(X);
        label2_kernel<<<100, 256, 0, stream>>>();
        sum_kernel<<<C, 256, 0, stream>>>(X);
        update_kernel<<<1, 1024, 0, stream>>>(it == NITER - 1 ? 1 : 0, out);
    }
}

// Round 21
// 2272.927 us; speedup vs baseline: 3.2214x; 1.0407x over previous
//
#include <hip/hip_runtime.h>
#include <stdint.h>

#define HW 25600
#define C  2048
#define K  10
#define NITER 20
#define RTOL_ 1e-5f
#define ATOL_ 1e-6f
#define NCH 8           // label c-chunks
#define CCH (C / NCH)   // 256 channels per chunk

typedef double vdbl2 __attribute__((ext_vector_type(2)));  // true clang vector

// ---------------- device state (fully re-derived every launch) ----------------
__device__ __align__(4) unsigned char g_valid[HW];
__device__ __align__(4) unsigned char g_labels[HW];
__device__ float g_tok_sq[HW];
__device__ float g_r[HW];
__device__ __align__(16) float  g_cent[K * C];
__device__ __align__(16) double g_cent64[K * C];   // f64 mirror for scalar loads
__device__ float g_csq[K];
__device__ int   g_counts[K];
__device__ unsigned g_done;
// scratch for parallel f64 partial reductions (f64 reassociation is safe:
// noise ~1e-16 rel, absorbed by the final f64->f32 rounding — R10-R16 evidence)
__device__ double g_part[NCH * K * HW];    // label partial dots (16.4 MB)
__device__ double g_spart[K * C];          // channel sums (f64)
__device__ double g_psq[8 * HW];           // prep partial sumsq
__device__ __align__(4) unsigned char g_pany[8 * HW];

// 16B nontemporal load of 4 floats via ext_vector double2 (allowed builtin type)
__device__ __forceinline__ float4 nt_load4(const float* p) {
    union { vdbl2 d; float4 f; } u;
    u.d = __builtin_nontemporal_load((const vdbl2*)p);
    return u.f;
}

// ---------------- prep A: per-chunk f64 partial sumsq + any ----------------
__global__ __launch_bounds__(256) void prepA_kernel(const float* __restrict__ X,
                                                    const float* __restrict__ mask) {
    const int chunk = blockIdx.x & 7;
    const int hw = (blockIdx.x >> 3) * 256 + threadIdx.x;
    const float mb = (mask[hw] > 0.0f) ? 1.0f : 0.0f;
    const float* xp = X + hw + (size_t)(chunk * 256) * HW;
    double a = 0.0;
    int n = 0;
    for (int cc = 0; cc < 256; ++cc) {
        float v = __builtin_nontemporal_load(xp + (size_t)cc * HW) * mb;
        n |= (v != 0.0f);
        a = fma((double)v, (double)v, a);
    }
    g_psq[chunk * HW + hw] = a;
    g_pany[chunk * HW + hw] = (unsigned char)n;
}

// ---------------- threefry2x32 (JAX partitionable), key=(0,42) ----------------
// counter=(hi=0, lo=i); 32-bit draw = out0 ^ out1 (CONFIRMED R6/R10-R18).
__device__ __forceinline__ uint32_t rotl32(uint32_t v, int d) {
    return (v << d) | (v >> (32 - d));
}

// ---------------- prepB + rng fused ----------------
__global__ __launch_bounds__(256) void rng_kernel() {
    const int hw = blockIdx.x * 256 + threadIdx.x;
    double s0 = (g_psq[0 * HW + hw] + g_psq[1 * HW + hw]) +
                (g_psq[2 * HW + hw] + g_psq[3 * HW + hw]);
    double s1 = (g_psq[4 * HW + hw] + g_psq[5 * HW + hw]) +
                (g_psq[6 * HW + hw] + g_psq[7 * HW + hw]);
    g_tok_sq[hw] = (float)(s0 + s1);
    int any = 0;
#pragma unroll
    for (int j = 0; j < 8; ++j) any |= g_pany[j * HW + hw];
    g_valid[hw] = any ? 1 : 0;

    const uint32_t k0 = 0u, k1 = 42u;
    uint32_t ks[3] = {k0, k1, k0 ^ k1 ^ 0x1BD11BDAu};
    uint32_t x0 = 0u + ks[0];
    uint32_t x1 = (uint32_t)hw + ks[1];
    const int rot[2][4] = {{13, 15, 26, 6}, {17, 29, 16, 24}};
#pragma unroll
    for (int g = 0; g < 5; ++g) {
#pragma unroll
        for (int j = 0; j < 4; ++j) {
            x0 += x1;
            x1 = rotl32(x1, rot[g & 1][j]);
            x1 ^= x0;
        }
        x0 += ks[(g + 1) % 3];
        x1 += ks[(g + 2) % 3] + (uint32_t)(g + 1);
    }
    uint32_t bits = x0 ^ x1;
    float u = __uint_as_float((bits >> 9) | 0x3f800000u) - 1.0f;
    g_r[hw] = any ? u : 2.0f;
}

// ---------------- init selection + gather + zero + csq ----------------
__global__ __launch_bounds__(1024) void select_kernel(const float* __restrict__ X,
                                                      const float* __restrict__ mask) {
    __shared__ unsigned long long wmin[16];
    __shared__ unsigned long long bcast;
    __shared__ int sh_idx[K];
    const int tid = threadIdx.x;
    const int lane = tid & 63, wv = tid >> 6;
    unsigned long long key[25];
#pragma unroll
    for (int j = 0; j < 25; ++j) {
        const int i = j * 1024 + tid;
        key[j] = ((unsigned long long)__float_as_uint(g_r[i]) << 32) | (unsigned)i;
    }
    for (int round = 0; round < K; ++round) {
        unsigned long long best = ~0ull;
#pragma unroll
        for (int j = 0; j < 25; ++j) best = (key[j] < best) ? key[j] : best;
#pragma unroll
        for (int off = 32; off > 0; off >>= 1) {
            unsigned long long o = __shfl_down(best, off, 64);
            best = (o < best) ? o : best;
        }
        if (lane == 0) wmin[wv] = best;
        __syncthreads();
        if (wv == 0) {
            unsigned long long b = (lane < 16) ? wmin[lane] : ~0ull;
#pragma unroll
            for (int off = 8; off > 0; off >>= 1) {
                unsigned long long o = __shfl_down(b, off, 64);
                b = (o < b) ? o : b;
            }
            if (lane == 0) { bcast = b; sh_idx[round] = (int)(b & 0xffffffffu); }
        }
        __syncthreads();
        const unsigned long long g = bcast;
#pragma unroll
        for (int j = 0; j < 25; ++j) if (key[j] == g) key[j] = ~0ull;
    }
    for (int e = tid; e < K * C; e += 1024) {
        int k = e >> 11, c = e & (C - 1);
        int id = sh_idx[k];
        float mb = (mask[id] > 0.0f) ? 1.0f : 0.0f;
        float v = X[(size_t)c * HW + id] * mb;
        g_cent[e] = v;
        g_cent64[e] = (double)v;
    }
    if (tid < K) g_counts[tid] = 0;
    if (tid == 0) g_done = 0u;
    __syncthreads();
    if (wv < K) {
        double a = 0.0;
        for (int c = lane; c < C; c += 64) {
            double v = (double)g_cent[wv * C + c];
            a = fma(v, v, a);
        }
#pragma unroll
        for (int off = 32; off > 0; off >>= 1) a += __shfl_down(a, off, 64);
        if (lane == 0) g_csq[wv] = (float)a;
    }
}

// ---------------- label pass 1: f64 partial dots, scalar-cached cent ----------------
__global__ __launch_bounds__(256) void label1_kernel(const float* __restrict__ X) {
    if (g_done) return;
    const int chunk = blockIdx.x & (NCH - 1);
    const int hw = (blockIdx.x >> 3) * 256 + threadIdx.x;
    const int c0 = chunk * CCH;
    const double* __restrict__ cp = g_cent64 + c0;  // [k*C + cc], wave-uniform
    double acc[K];
#pragma unroll
    for (int k = 0; k < K; ++k) acc[k] = 0.0;
    const float* xp = X + hw + (size_t)c0 * HW;
#pragma unroll 8
    for (int cc = 0; cc < CCH; ++cc) {
        const double x = (double)__builtin_nontemporal_load(xp + (size_t)cc * HW);
#pragma unroll
        for (int k = 0; k < K; ++k) acc[k] = fma(x, cp[k * C + cc], acc[k]);
    }
#pragma unroll
    for (int k = 0; k < K; ++k) g_part[(chunk * K + k) * HW + hw] = acc[k];
}

// ---------------- label pass 2: combine 8, f32 d2 grid, argmin, hist ----------------
__global__ __launch_bounds__(256) void label2_kernel() {
#pragma clang fp contract(off)
    if (g_done) return;
    __shared__ int shist[K];
    const int t = threadIdx.x;
    if (t < K) shist[t] = 0;
    __syncthreads();
    const int hw = blockIdx.x * 256 + t;
    const float tsq = g_tok_sq[hw];
    float best = INFINITY;
    int bl = 0;
#pragma unroll
    for (int k = 0; k < K; ++k) {
        double p[NCH];
#pragma unroll
        for (int j = 0; j < NCH; ++j)
            p[j] = __builtin_nontemporal_load(&g_part[(j * K + k) * HW + hw]);
        double d = ((p[0] + p[1]) + (p[2] + p[3])) + ((p[4] + p[5]) + (p[6] + p[7]));
        float dotf = (float)d;               // correctly-rounded f32 dot
        float twod = 2.0f * dotf;            // exact
        float d2 = (tsq - twod) + g_csq[k];  // reference's f32 grid
        if (d2 < best) { best = d2; bl = k; }
    }
    const int valid = g_valid[hw];
    g_labels[hw] = valid ? (unsigned char)bl : (unsigned char)255;
    if (valid) atomicAdd(&shist[bl], 1);
    __syncthreads();
    if (t < K) atomicAdd(&g_counts[t], shist[t]);
}

// ---------------- sum pass: block per channel, slot-major LDS ----------------
// 2048 blocks; slot k of lane l at sacc[wv][k*64 + l]: bank = 2l mod 32
// -> 2-way aliasing = free (m136). Per-lane order identical to R16.
__global__ __launch_bounds__(256) void sum_kernel(const float* __restrict__ X) {
    if (g_done) return;
    __shared__ double sacc[4][11 * 64];  // 22.5 KB
    const int c = blockIdx.x;
    const int wv = threadIdx.x >> 6, lane = threadIdx.x & 63;
    double* slots = &sacc[wv][lane];     // slot k at slots[k*64]
#pragma unroll
    for (int k = 0; k < 11; ++k) slots[k * 64] = 0.0;
    const int base = wv * (HW / 4);      // quarter-row (1600 float4)
    const float* xr = X + (size_t)c * HW + base;
    const unsigned* lw = (const unsigned*)(g_labels + base);
    for (int t = 0; t < 25; ++t) {
        const int idx = t * 64 + lane;
        const float4 x = nt_load4(xr + idx * 4);
        const unsigned w = lw[idx];
        const int l0 = min((int)(w & 255u), 10);
        const int l1 = min((int)((w >> 8) & 255u), 10);
        const int l2 = min((int)((w >> 16) & 255u), 10);
        const int l3 = min((int)(w >> 24), 10);
        slots[l0 * 64] += (double)x.x;
        slots[l1 * 64] += (double)x.y;
        slots[l2 * 64] += (double)x.z;
        slots[l3 * 64] += (double)x.w;
    }
    double acc[K];
#pragma unroll
    for (int k = 0; k < K; ++k) acc[k] = slots[k * 64];
#pragma unroll
    for (int k = 0; k < K; ++k) {
#pragma unroll
        for (int off = 32; off > 0; off >>= 1) acc[k] += __shfl_down(acc[k], off, 64);
    }
    __shared__ double comb[4][K];
    if (lane == 0) {
#pragma unroll
        for (int k = 0; k < K; ++k) comb[wv][k] = acc[k];
    }
    __syncthreads();
    if (threadIdx.x < K) {
        const int k = threadIdx.x;
        g_spart[k * C + c] = (comb[0][k] + comb[1][k]) + (comb[2][k] + comb[3][k]);
    }
}

// ---------------- update / convergence / csq ----------------
__global__ __launch_bounds__(1024) void update_kernel(int last, float* __restrict__ out) {
#pragma clang fp contract(off)
    __shared__ float sh_counts[K];
    __shared__ int s_conv;
    __shared__ unsigned s_done;
    const int tid = threadIdx.x;
    if (tid == 0) { s_conv = 1; s_done = g_done; }
    if (tid < K) sh_counts[tid] = (float)g_counts[tid];
    __syncthreads();
    const bool dn = (s_done != 0);
    float newv[20], oldv[20];
    int convLocal = 1;
#pragma unroll
    for (int j = 0; j < 20; ++j) {
        int e = tid + j * 1024;
        int k = e >> 11;
        float cnt = sh_counts[k];
        float cv = g_cent[e];
        float sumf = (float)g_spart[e];   // f64 total -> f32 once
        float nv = (cnt > 0.0f) ? (sumf / fmaxf(cnt, 1.0f)) : cv;
        newv[j] = nv;
        oldv[j] = cv;
        float tol = RTOL_ * fabsf(nv);   // rounded mul
        tol = ATOL_ + tol;               // rounded add
        float diff = fabsf(cv - nv);
        if (!(diff <= tol)) convLocal = 0;
    }
    if (!convLocal) atomicAnd(&s_conv, 0);
    __syncthreads();
    const bool conv = (s_conv != 0);
    const bool upd = (!dn && !conv);
#pragma unroll
    for (int j = 0; j < 20; ++j) {
        int e = tid + j * 1024;
        float fv = upd ? newv[j] : oldv[j];
        if (upd) { g_cent[e] = fv; g_cent64[e] = (double)fv; }
        if (last) out[e] = fv;
    }
    if (tid == 0 && conv && !dn) g_done = 1u;
    if (tid < K) g_counts[tid] = 0;
    __syncthreads();
    const int wv = tid >> 6, lane = tid & 63;
    if (wv < K) {
        double a = 0.0;
        for (int c = lane; c < C; c += 64) {
            double v = (double)g_cent[wv * C + c];
            a = fma(v, v, a);
        }
#pragma unroll
        for (int off = 32; off > 0; off >>= 1) a += __shfl_down(a, off, 64);
        if (lane == 0) g_csq[wv] = (float)a;
    }
}

extern "C" void kernel_launch(void* const* d_in, const int* in_sizes, int n_in,
                              void* d_out, int out_size, void* d_ws, size_t ws_size,
                              hipStream_t stream) {
    const float* X = (const float*)d_in[0];     // [2048, 160*160] flat
    const float* mask = (const float*)d_in[1];  // [160*160]
    float* out = (float*)d_out;                 // [10, 2048]
    (void)in_sizes; (void)n_in; (void)out_size; (void)d_ws; (void)ws_size;

    prepA_kernel<<<800, 256, 0, stream>>>(X, mask);
    rng_kernel<<<100, 256, 0, stream>>>();
    select_kernel<<<1, 1024, 0, stream>>>(X, mask);
    for (int it = 0; it < NITER; ++it) {
        label1_kernel<<<800, 256, 0, stream>>>(X);
        label2_kernel<<<100, 256, 0, stream>>>();
        sum_kernel<<<C, 256, 0, stream>>>(X);
        update_kernel<<<1, 1024, 0, stream>>>(it == NITER - 1 ? 1 : 0, out);
    }
}